// Round 9
// baseline (202.813 us; speedup 1.0000x reference)
//
#include <hip/hip_runtime.h>
#include <math.h>

// Problem constants (B=4, S=2048, D_MODEL=512, H=8, DQ=64)
#define BATCH 4
#define SEQ   2048
#define DM    512
#define NH    8
#define DQ    64
#define BS    (BATCH*SEQ)     // 8192 rows
#define BPAD  72              // bf16 LDS row stride (144 B)
#define APAD  72              // padded tile stride in gemm k-loops
#define CPAD  132             // epilogue C-tile stride (bf16 elems / fp32 elems)

// q pre-scale: 1/sqrt(64) * log2(e), so softmax uses native 2^x (v_exp_f32)
#define QSCALE 0.18033688011112042f

typedef short  short8   __attribute__((ext_vector_type(8)));
typedef float  floatx4  __attribute__((ext_vector_type(4)));
typedef float  floatx16 __attribute__((ext_vector_type(16)));
typedef unsigned short ushort8 __attribute__((ext_vector_type(8)));

// cheap bf16: round-half-up (1 add + shift). Ties-only delta vs RNE.
__device__ __forceinline__ unsigned short f2bf(float f) {
    return (unsigned short)((__float_as_uint(f) + 0x8000u) >> 16);
}
// pack two floats -> two bf16 in one u32 (lo = a, hi = b): 2 adds + 1 v_perm
__device__ __forceinline__ unsigned pack2bf(float a, float b) {
    unsigned ua = __float_as_uint(a) + 0x8000u;
    unsigned ub = __float_as_uint(b) + 0x8000u;
    return __builtin_amdgcn_perm(ub, ua, 0x07060302u);  // {ub[3],ub[2],ua[3],ua[2]}
}

// ---------------------------------------------------------------------------
// convert_w: pack weights to bf16 B^T layout [n][k].
//   which 0..2: wt[which][h*64+d][dd] = W[h][dd][d]  (qkv projections)
//   which 3:    wo[o][c] = Wout[o][c]                 (already B^T)
// grid (256, 4).
// ---------------------------------------------------------------------------
__global__ __launch_bounds__(256) void convert_w_kernel(
    const float* __restrict__ Wq, const float* __restrict__ Wk,
    const float* __restrict__ Wv, const float* __restrict__ Wo,
    unsigned short* __restrict__ wt, unsigned short* __restrict__ wo)
{
    const int which = blockIdx.y;
    const int idx = blockIdx.x * 256 + threadIdx.x;   // 65536 per matrix
    if (which == 3) {
        float4 v = *(const float4*)(Wo + (size_t)idx * 4);
        uint2 o;
        o.x = pack2bf(v.x, v.y);
        o.y = pack2bf(v.z, v.w);
        *(uint2*)(wo + (size_t)idx * 4) = o;
    } else {
        const float* W = (which == 0) ? Wq : (which == 1) ? Wk : Wv;
        const int n   = idx >> 7;          // 0..511  (h*64+d)
        const int dd0 = (idx & 127) * 4;
        const int h = n >> 6, d = n & 63;
        uint2 o;
        o.x = pack2bf(W[((size_t)h * DM + dd0 + 0) * DQ + d],
                      W[((size_t)h * DM + dd0 + 1) * DQ + d]);
        o.y = pack2bf(W[((size_t)h * DM + dd0 + 2) * DQ + d],
                      W[((size_t)h * DM + dd0 + 3) * DQ + d]);
        *(uint2*)(wt + (size_t)which * (DM * DM) + (size_t)n * DM + dd0) = o;
    }
}

// ---------------------------------------------------------------------------
// qkv GEMM: 128x128 tile, BK=64, register-prefetched staging, and an
// LDS-staged COALESCED epilogue (the old per-element global stores were the
// residue whale: the v-transpose scattered 2B stores 4KB apart = ~32x write
// amplification). Operand-order trick: MFMA C-layout register quads are
// column strips, so writing the TRANSPOSE of the register tile into LDS is
// contiguous b64 writes. q/k use swapped operands (regs = C^T -> LDS holds
// C[m][n], read rows -> d-contiguous stores); v uses natural order (LDS
// holds C^T[n][m], read rows -> s-contiguous stores). All global stores
// become 128B dwordx4 runs.
// grid (64, 4, 3), block 256.
// ---------------------------------------------------------------------------
__global__ __launch_bounds__(256) void qkv_gemm_kernel(
    const float* __restrict__ Xq, const float* __restrict__ Xk,
    const float* __restrict__ Xv, const unsigned short* __restrict__ wt,
    unsigned short* __restrict__ Oq, unsigned short* __restrict__ Ok,
    unsigned short* __restrict__ Ovt)
{
    __shared__ __align__(16) char smem[36864];
    unsigned short (*As)[APAD] = (unsigned short (*)[APAD])smem;            // 128x72
    unsigned short (*Bs)[APAD] = (unsigned short (*)[APAD])(smem + 18432);  // 128x72
    unsigned short (*Cs)[CPAD] = (unsigned short (*)[CPAD])smem;            // 128x132 (33792 B)

    const int which = blockIdx.z;
    const float* X = (which == 0) ? Xq : (which == 1) ? Xk : Xv;
    const unsigned short* Bt = wt + (size_t)which * (DM * DM);

    const int m0 = blockIdx.x * 128;
    const int n0 = blockIdx.y * 128;
    const int t = threadIdx.x, w = t >> 6, lane = t & 63;
    const int quad = lane >> 4, qr = lane & 15;
    const int arow = t >> 4;           // A staging: 16 rows/pass
    const int acol = (t & 15) * 4;     // float4 col
    const int brow = t >> 3;           // B staging: 32 rows/pass
    const int bcol = (t & 7) * 8;      // ushort8 col
    const int mw = 64 * (w >> 1), nw = 64 * (w & 1);

    floatx4 acc[4][4] = {};
    float4  areg[8];
    ushort8 breg[4];

    #pragma unroll
    for (int i = 0; i < 8; ++i)
        areg[i] = *(const float4*)(X + (size_t)(m0 + i * 16 + arow) * DM + acol);
    #pragma unroll
    for (int i = 0; i < 4; ++i)
        breg[i] = *(const ushort8*)(Bt + (size_t)(n0 + i * 32 + brow) * DM + bcol);

    for (int k0 = 0; k0 < DM; k0 += 64) {
        __syncthreads();
        #pragma unroll
        for (int i = 0; i < 8; ++i) {
            uint2 o;
            o.x = pack2bf(areg[i].x, areg[i].y);
            o.y = pack2bf(areg[i].z, areg[i].w);
            *(uint2*)&As[i * 16 + arow][acol] = o;
        }
        #pragma unroll
        for (int i = 0; i < 4; ++i)
            *(ushort8*)&Bs[i * 32 + brow][bcol] = breg[i];
        __syncthreads();

        if (k0 + 64 < DM) {
            #pragma unroll
            for (int i = 0; i < 8; ++i)
                areg[i] = *(const float4*)(X + (size_t)(m0 + i * 16 + arow) * DM + k0 + 64 + acol);
            #pragma unroll
            for (int i = 0; i < 4; ++i)
                breg[i] = *(const ushort8*)(Bt + (size_t)(n0 + i * 32 + brow) * DM + k0 + 64 + bcol);
        }

        #pragma unroll
        for (int kh = 0; kh < 2; ++kh) {
            short8 af[4], bf[4];
            #pragma unroll
            for (int si = 0; si < 4; ++si)
                af[si] = *(const short8*)&As[mw + 16 * si + qr][kh * 32 + quad * 8];
            #pragma unroll
            for (int sj = 0; sj < 4; ++sj)
                bf[sj] = *(const short8*)&Bs[nw + 16 * sj + qr][kh * 32 + quad * 8];
            if (which < 2) {
                // swapped operands: regs hold C^T (col=m, row=n)
                #pragma unroll
                for (int si = 0; si < 4; ++si)
                    #pragma unroll
                    for (int sj = 0; sj < 4; ++sj)
                        acc[si][sj] = __builtin_amdgcn_mfma_f32_16x16x32_bf16(
                            bf[sj], af[si], acc[si][sj], 0, 0, 0);
            } else {
                // natural: regs hold C (col=n, row=m)
                #pragma unroll
                for (int si = 0; si < 4; ++si)
                    #pragma unroll
                    for (int sj = 0; sj < 4; ++sj)
                        acc[si][sj] = __builtin_amdgcn_mfma_f32_16x16x32_bf16(
                            af[si], bf[sj], acc[si][sj], 0, 0, 0);
            }
        }
    }

    __syncthreads();   // k-loop LDS reads done before Cs overwrite

    if (which < 2) {
        // regs = C^T: col = m = mw+16si+qr, row = n = nw+16sj+quad*4+r
        // write transpose -> Cs[m][n]: consecutive n per reg quad = b64 write
        const float osc = (which == 0) ? QSCALE : 1.0f;
        #pragma unroll
        for (int si = 0; si < 4; ++si)
            #pragma unroll
            for (int sj = 0; sj < 4; ++sj) {
                uint2 pk;
                pk.x = pack2bf(acc[si][sj][0] * osc, acc[si][sj][1] * osc);
                pk.y = pack2bf(acc[si][sj][2] * osc, acc[si][sj][3] * osc);
                *(uint2*)&Cs[mw + 16 * si + qr][nw + 16 * sj + quad * 4] = pk;
            }
        __syncthreads();
        // read rows of Cs: thread -> (row = t>>1, 64-col half), store 128B runs
        unsigned short* O = (which == 0) ? Oq : Ok;
        const int row = t >> 1;              // m index 0..127
        const int ch  = (t & 1) * 64;        // col half
        const int m = m0 + row, b = m >> 11, s = m & (SEQ - 1);
        const int col = n0 + ch, hh = col >> 6;
        unsigned short* dst = O + ((size_t)(b * NH + hh) * SEQ + s) * DQ;
        #pragma unroll
        for (int i = 0; i < 8; ++i)
            *(ushort8*)(dst + i * 8) = *(const ushort8*)&Cs[row][ch + i * 8];
    } else {
        // regs = C: col = n = nw+16sj+qr, row = m = mw+16si+quad*4+r
        // write transpose -> Cs[n][m]: consecutive m per reg quad = b64 write
        #pragma unroll
        for (int si = 0; si < 4; ++si)
            #pragma unroll
            for (int sj = 0; sj < 4; ++sj) {
                uint2 pk;
                pk.x = pack2bf(acc[si][sj][0], acc[si][sj][1]);
                pk.y = pack2bf(acc[si][sj][2], acc[si][sj][3]);
                *(uint2*)&Cs[nw + 16 * sj + qr][mw + 16 * si + quad * 4] = pk;
            }
        __syncthreads();
        // read rows of Cs[n][m]: store s-contiguous 128B runs of Ovt[b,h,d,s]
        const int row = t >> 1;              // n index 0..127
        const int ch  = (t & 1) * 64;        // s half
        const int col = n0 + row, hh = col >> 6, d = col & 63;
        const int b = m0 >> 11;              // 128-row tile never crosses batch
        unsigned short* dst = Ovt + ((size_t)(b * NH + hh) * DQ + d) * SEQ + (m0 & (SEQ - 1)) + ch;
        #pragma unroll
        for (int i = 0; i < 8; ++i)
            *(ushort8*)(dst + i * 8) = *(const ushort8*)&Cs[row][ch + i * 8];
    }
}

// ---------------------------------------------------------------------------
// out GEMM: 64x128 tile, BK=64, register-prefetched staging, swapped-operand
// MFMA (regs = C^T) + LDS-staged fp32 epilogue -> 128B dwordx4 stores.
// A = heads bf16 [8192x512] (flat view == reference reshape), Bt = Wout bf16
// [o][c]. Output fp32 d_out. grid (128, 4), block 256; wave tile 32x64.
// ---------------------------------------------------------------------------
__global__ __launch_bounds__(256) void out_gemm_kernel(
    const unsigned short* __restrict__ A, const unsigned short* __restrict__ Bt,
    float* __restrict__ C)
{
    __shared__ __align__(16) char smem[33792];
    unsigned short (*As)[APAD] = (unsigned short (*)[APAD])smem;            // 64x72
    unsigned short (*Bs)[APAD] = (unsigned short (*)[APAD])(smem + 9216);   // 128x72
    float          (*Cf)[CPAD] = (float (*)[CPAD])smem;                     // 64x132 f32 (33792 B)

    const int m0 = blockIdx.x * 64;
    const int n0 = blockIdx.y * 128;
    const int t = threadIdx.x, w = t >> 6, lane = t & 63;
    const int quad = lane >> 4, qr = lane & 15;
    const int brow = t >> 3;           // 32 rows/pass
    const int bcol = (t & 7) * 8;
    const int mw = 32 * (w >> 1), nw = 64 * (w & 1);

    floatx4 acc[2][4] = {};
    ushort8 areg[2], breg[4];

    #pragma unroll
    for (int i = 0; i < 2; ++i)
        areg[i] = *(const ushort8*)(A + (size_t)(m0 + i * 32 + brow) * DM + bcol);
    #pragma unroll
    for (int i = 0; i < 4; ++i)
        breg[i] = *(const ushort8*)(Bt + (size_t)(n0 + i * 32 + brow) * DM + bcol);

    for (int k0 = 0; k0 < DM; k0 += 64) {
        __syncthreads();
        #pragma unroll
        for (int i = 0; i < 2; ++i)
            *(ushort8*)&As[i * 32 + brow][bcol] = areg[i];
        #pragma unroll
        for (int i = 0; i < 4; ++i)
            *(ushort8*)&Bs[i * 32 + brow][bcol] = breg[i];
        __syncthreads();

        if (k0 + 64 < DM) {
            #pragma unroll
            for (int i = 0; i < 2; ++i)
                areg[i] = *(const ushort8*)(A + (size_t)(m0 + i * 32 + brow) * DM + k0 + 64 + bcol);
            #pragma unroll
            for (int i = 0; i < 4; ++i)
                breg[i] = *(const ushort8*)(Bt + (size_t)(n0 + i * 32 + brow) * DM + k0 + 64 + bcol);
        }

        #pragma unroll
        for (int kh = 0; kh < 2; ++kh) {
            short8 af[2], bf[4];
            #pragma unroll
            for (int si = 0; si < 2; ++si)
                af[si] = *(const short8*)&As[mw + 16 * si + qr][kh * 32 + quad * 8];
            #pragma unroll
            for (int sj = 0; sj < 4; ++sj)
                bf[sj] = *(const short8*)&Bs[nw + 16 * sj + qr][kh * 32 + quad * 8];
            #pragma unroll
            for (int si = 0; si < 2; ++si)
                #pragma unroll
                for (int sj = 0; sj < 4; ++sj)
                    acc[si][sj] = __builtin_amdgcn_mfma_f32_16x16x32_bf16(
                        bf[sj], af[si], acc[si][sj], 0, 0, 0);   // swapped: regs = C^T
        }
    }

    __syncthreads();
    // regs = C^T: col = m = mw+16si+qr, row = n = nw+16sj+quad*4+r
    // write transpose -> Cf[m][n]: float4 writes
    #pragma unroll
    for (int si = 0; si < 2; ++si)
        #pragma unroll
        for (int sj = 0; sj < 4; ++sj)
            *(floatx4*)&Cf[mw + 16 * si + qr][nw + 16 * sj + quad * 4] = acc[si][sj];
    __syncthreads();
    // read rows: thread -> (row = t>>2, 32-col quarter), 128B dwordx4 stores
    const int row = t >> 2;
    const int ch  = (t & 3) * 32;
    float* dst = C + (size_t)(m0 + row) * DM + n0 + ch;
    #pragma unroll
    for (int i = 0; i < 8; ++i)
        *(floatx4*)(dst + i * 4) = *(const floatx4*)&Cf[row][ch + i * 4];
}

// ---------------------------------------------------------------------------
// flash attention v6 (unchanged from R8): 32x32x16 MFMA, 64 q-rows/block,
// wave (qh,kh) computes S^T[32kv][32q], P via wave-private Ps quadrant,
// per-wave partial O combined cross-kh through aliased LDS at the end.
// Fixed-reference base-2 softmax, raw v_exp_f32, K/V register prefetch.
// 36 KB LDS -> 4 blocks/CU. grid = (32, 8, 4), block 256.
// ---------------------------------------------------------------------------
__global__ __launch_bounds__(256, 4) void attn_kernel(
    const unsigned short* __restrict__ Qp, const unsigned short* __restrict__ Kp,
    const unsigned short* __restrict__ Vtp, unsigned short* __restrict__ Hd)
{
    __shared__ unsigned short smem[4 * 64 * BPAD];   // 36 KB
    unsigned short (*Qs)[BPAD]  = (unsigned short (*)[BPAD])(smem);
    unsigned short (*Ks)[BPAD]  = (unsigned short (*)[BPAD])(smem + 64 * BPAD);
    unsigned short (*Vts)[BPAD] = (unsigned short (*)[BPAD])(smem + 2 * 64 * BPAD);
    unsigned short (*Ps)[BPAD]  = (unsigned short (*)[BPAD])(smem + 3 * 64 * BPAD);

    const int s0 = blockIdx.x * 64;
    const int h  = blockIdx.y;
    const int b  = blockIdx.z;
    const size_t bh    = (size_t)(b * NH + h);
    const size_t base  = bh * SEQ * DQ;       // [b,h,s,d]
    const size_t vbase = bh * DQ * SEQ;       // [b,h,d,s]

    const int t    = threadIdx.x;
    const int w    = t >> 6;
    const int lane = t & 63;
    const int qh   = w >> 1;      // q-half (rows 32qh..32qh+31)
    const int kh   = w & 1;       // kv-half within each 64-kv tile
    const int ln31 = lane & 31;
    const int lh   = lane >> 5;   // lane half

    // ---- stage Q tile ----
    {
        const unsigned short* g = Qp + base + (size_t)s0 * DQ;
        #pragma unroll
        for (int i = 0; i < 2; ++i) {
            const int c = t + 256 * i;
            const int row = c >> 3, col8 = (c & 7) * 8;
            *(ushort8*)&Qs[row][col8] = *(const ushort8*)(g + row * DQ + col8);
        }
    }
    __syncthreads();
    short8 bq[4];
    #pragma unroll
    for (int s = 0; s < 4; ++s)
        bq[s] = *(const short8*)&Qs[32 * qh + ln31][16 * s + lh * 8];

    floatx16 accO[2] = {};   // partial O[32q][64dv]
    float l_lane = 0.f;

    ushort8 kreg[2], vreg[2];
    {
        const unsigned short* gk = Kp + base;
        const unsigned short* gv = Vtp + vbase;
        #pragma unroll
        for (int i = 0; i < 2; ++i) {
            const int c = t + 256 * i;
            const int row = c >> 3, col8 = (c & 7) * 8;
            kreg[i] = *(const ushort8*)(gk + row * DQ + col8);
            vreg[i] = *(const ushort8*)(gv + (size_t)row * SEQ + col8);
        }
    }

    for (int kt = 0; kt < SEQ; kt += 64) {
        __syncthreads();
        #pragma unroll
        for (int i = 0; i < 2; ++i) {
            const int c = t + 256 * i;
            const int row = c >> 3, col8 = (c & 7) * 8;
            *(ushort8*)&Ks[row][col8]  = kreg[i];
            *(ushort8*)&Vts[row][col8] = vreg[i];
        }
        __syncthreads();

        if (kt + 64 < SEQ) {
            const unsigned short* gk = Kp + base + (size_t)(kt + 64) * DQ;
            const unsigned short* gv = Vtp + vbase + (kt + 64);
            #pragma unroll
            for (int i = 0; i < 2; ++i) {
                const int c = t + 256 * i;
                const int row = c >> 3, col8 = (c & 7) * 8;
                kreg[i] = *(const ushort8*)(gk + row * DQ + col8);
                vreg[i] = *(const ushort8*)(gv + (size_t)row * SEQ + col8);
            }
        }

        floatx16 z = {};
        #pragma unroll
        for (int s = 0; s < 4; ++s) {
            const short8 ak = *(const short8*)&Ks[32 * kh + ln31][16 * s + lh * 8];
            z = __builtin_amdgcn_mfma_f32_32x32x16_bf16(ak, bq[s], z, 0, 0, 0);
        }

        #pragma unroll
        for (int g = 0; g < 4; ++g) {
            const float p0 = __builtin_amdgcn_exp2f(z[4 * g + 0]);
            const float p1 = __builtin_amdgcn_exp2f(z[4 * g + 1]);
            const float p2 = __builtin_amdgcn_exp2f(z[4 * g + 2]);
            const float p3 = __builtin_amdgcn_exp2f(z[4 * g + 3]);
            l_lane += (p0 + p1) + (p2 + p3);
            uint2 pk;
            pk.x = pack2bf(p0, p1);
            pk.y = pack2bf(p2, p3);
            *(uint2*)&Ps[32 * qh + ln31][32 * kh + 8 * g + 4 * lh] = pk;
        }

        short8 ap[2];
        ap[0] = *(const short8*)&Ps[32 * qh + ln31][32 * kh + lh * 8];
        ap[1] = *(const short8*)&Ps[32 * qh + ln31][32 * kh + 16 + lh * 8];
        #pragma unroll
        for (int a = 0; a < 2; ++a) {
            #pragma unroll
            for (int s = 0; s < 2; ++s) {
                const short8 bv = *(const short8*)&Vts[32 * a + ln31][32 * kh + 16 * s + lh * 8];
                accO[a] = __builtin_amdgcn_mfma_f32_32x32x16_bf16(ap[s], bv, accO[a], 0, 0, 0);
            }
        }
    }

    float l2 = l_lane + __shfl_xor(l_lane, 32);
    float* Obuf = (float*)(smem + 64 * BPAD);
    float* lbuf = (float*)(smem + 3 * 64 * BPAD);
    __syncthreads();

    if (kh == 0) {
        if (lane < 32) lbuf[qh * 32 + lane] = l2;
        #pragma unroll
        for (int a = 0; a < 2; ++a)
            #pragma unroll
            for (int r = 0; r < 16; ++r) {
                const int qrow = (r & 3) + 8 * (r >> 2) + 4 * lh;
                Obuf[(32 * qh + qrow) * 66 + 32 * a + ln31] = accO[a][r];
            }
    }
    __syncthreads();

    if (kh == 1) {
        const float ltot = l2 + lbuf[qh * 32 + ln31];
        if (lane < 32) lbuf[64 + qh * 32 + lane] = 1.0f / ltot;
        #pragma unroll
        for (int a = 0; a < 2; ++a)
            #pragma unroll
            for (int r = 0; r < 16; ++r) {
                const int qrow = (r & 3) + 8 * (r >> 2) + 4 * lh;
                const float o = accO[a][r] + Obuf[(32 * qh + qrow) * 66 + 32 * a + ln31];
                const float iv = lbuf[64 + qh * 32 + qrow];
                Hd[base + (size_t)(s0 + 32 * qh + qrow) * DQ + 32 * a + ln31] = f2bf(o * iv);
            }
    }
}

// ---------------------------------------------------------------------------
// kernel_launch
// Workspace (ushort units):
//   wt:    0        (3 x 262144)    qkv weights bf16, B^T [h*64+d][dd]
//   wo:    786432   (262144)        Wout bf16 [o][c]
//   q_ws:  1048576  (4194304)       q*QSCALE bf16 [b,h,s,d]
//   k_ws:  5242880  (4194304)       k bf16 [b,h,s,d]
//   vt_ws: 9437184  (4194304)       v bf16 [b,h,d,s]
//   h_ws:  13631488 (4194304)       heads bf16 (flat GEMM-A view)
// total ~34 MB
// ---------------------------------------------------------------------------
extern "C" void kernel_launch(void* const* d_in, const int* in_sizes, int n_in,
                              void* d_out, int out_size, void* d_ws, size_t ws_size,
                              hipStream_t stream) {
    const float* xq = (const float*)d_in[0];
    const float* xk = (const float*)d_in[1];
    const float* xv = (const float*)d_in[2];
    const float* Qw = (const float*)d_in[3];
    const float* Kw = (const float*)d_in[4];
    const float* Vw = (const float*)d_in[5];
    const float* Wo = (const float*)d_in[6];
    float* out = (float*)d_out;

    unsigned short* ws = (unsigned short*)d_ws;
    unsigned short* wt    = ws;
    unsigned short* wo    = ws + (size_t)786432;
    unsigned short* q_ws  = ws + (size_t)1048576;
    unsigned short* k_ws  = ws + (size_t)5242880;
    unsigned short* vt_ws = ws + (size_t)9437184;
    unsigned short* h_ws  = ws + (size_t)13631488;

    convert_w_kernel<<<dim3(256, 4), 256, 0, stream>>>(Qw, Kw, Vw, Wo, wt, wo);
    qkv_gemm_kernel<<<dim3(64, 4, 3), 256, 0, stream>>>(xq, xk, xv, wt, q_ws, k_ws, vt_ws);
    attn_kernel<<<dim3(SEQ / 64, NH, BATCH), 256, 0, stream>>>(q_ws, k_ws, vt_ws, h_ws);
    out_gemm_kernel<<<dim3(128, 4), 256, 0, stream>>>(h_ws, wo, out);
}